// Round 6
// baseline (17.131 us; speedup 1.0000x reference)
//
#include <hip/hip_runtime.h>

#define D_DIM 32768
#define NT 64
#define NKEYS 120
#define NG 16          // timestamp groups (4 t each)
#define NC 16          // dim chunks (2048 dims each)
#define CW 2048        // chunk width in dims
#define TPB 1024       // 16 waves

__constant__ int c_feat_idx[NKEYS] = {
    557, 581, 553, 551, 92, 554, 579, 570, 573, 577,
    565, 286, 555, 549, 13, 550, 63, 580, 556, 564,
    0, 576, 567, 552, 578, 588, 597, 566, 571, 44,
    572, 574, 14, 582, 381, 594, 4, 593, 218, 25,
    84, 592, 3, 591, 547, 561, 562, 548, 319, 596,
    558, 563, 87, 65, 599, 17, 88, 2, 49, 309,
    6, 81, 15, 590, 589, 43, 273, 420, 546, 568,
    400, 277, 202, 287, 434, 435, 423, 431, 301, 417,
    412, 205, 179, 327, 176, 442, 172, 450, 391, 163,
    154, 480, 485, 490, 491, 498, 503, 507, 509, 452,
    239, 388, 219, 303, 292, 310, 316, 320, 322, 324,
    326, 330, 336, 263, 262, 339, 340, 256, 345, 347};

__device__ __forceinline__ int level_idx(float x) {
    // replicate: clip(x,-5,5); round(((x+5)/10)*2047) half-to-even; clip 0..2047
    x = fminf(fmaxf(x, -5.0f), 5.0f);
    float v = (x + 5.0f) / 10.0f * 2047.0f;
    int i = (int)rintf(v);
    return min(max(i, 0), 2047);
}

// K1: grid 256 = 16 t-groups x 16 dim-chunks, 1024 threads.
// Every gathered row is read by the block as ONE contiguous 8KB span
// (16 waves x 512B), instead of R1's isolated 512B slice per row.
// No LDS, no barrier: each wave owns its 128 dims for this t-group.
__global__ __launch_bounds__(TPB) void hdc_partial_kernel(
    const float* __restrict__ input,
    const float* __restrict__ feat,
    const float* __restrict__ Wx,
    const float* __restrict__ Wy,
    const float* __restrict__ Wz,
    const float* __restrict__ Wt,
    const float* __restrict__ keys,
    int* __restrict__ ws)
{
    const int tid  = threadIdx.x;
    const int wave = __builtin_amdgcn_readfirstlane(tid >> 6);  // 0..15
    const int lane = tid & 63;
    const int g    = blockIdx.x >> 4;       // t-group 0..15
    const int c    = blockIdx.x & 15;       // dim chunk 0..15
    const int d0   = c * CW + wave * 128 + lane * 2;   // lane's two dims

    // ---- wave-uniform scalar prologue (no LDS, no barrier) ----
    int rx[4], ry[4], rz[4], rt[4];
#pragma unroll
    for (int k = 0; k < 4; ++k) {
        int t = g * 4 + k;                  // uniform (g from blockIdx)
        rx[k] = __builtin_amdgcn_readfirstlane(level_idx(input[t * 4 + 1]));
        ry[k] = __builtin_amdgcn_readfirstlane(level_idx(input[t * 4 + 2]));
        rz[k] = __builtin_amdgcn_readfirstlane(level_idx(input[t * 4 + 3]));
        int it = (int)rintf((float)t / 64.0f * 63.0f);
        rt[k] = __builtin_amdgcn_readfirstlane(min(max(it, 0), NT - 1));
    }
    const int nk = (g < 8) ? 8 : 7;                    // 8*8 + 8*7 = 120 keys
    const int j0 = (g < 8) ? g * 8 : 64 + (g - 8) * 7;
    int fx[8];
#pragma unroll
    for (int k = 0; k < 8; ++k) {
        int j = j0 + ((k < nk) ? k : 0);
        float fv = feat[c_feat_idx[j]];
        fv = fminf(fmaxf(fv, -1.0f), 1.0f);
        fx[k] = __builtin_amdgcn_readfirstlane((int)rintf((fv + 1.0f) * 0.5f * 32768.0f));
    }

    // ---- sample part: 4 timestamps of this group ----
    unsigned sg0 = 0u, sg1 = 0u;
    int a30 = 0, a31 = 0;
#pragma unroll
    for (int k = 0; k < 4; ++k) {
        float2 x = *(const float2*)(Wx + ((size_t)rx[k] << 15) + d0);
        float2 y = *(const float2*)(Wy + ((size_t)ry[k] << 15) + d0);
        float2 z = *(const float2*)(Wz + ((size_t)rz[k] << 15) + d0);
        float2 w = *(const float2*)(Wt + ((size_t)rt[k] << 15) + d0);
        float sA = x.x + y.x + z.x;          // in {+-1, +-3} exactly
        float sB = x.y + y.y + z.y;
        sg0 ^= __float_as_uint(sA * w.x);
        sg1 ^= __float_as_uint(sB * w.y);
        a30 += (fabsf(sA) > 2.0f) ? 1 : 0;
        a31 += (fabsf(sB) > 2.0f) ? 1 : 0;
    }

    // ---- feature part: this group's keys ----
    int f0 = 0, f1 = 0;                      // exact integer sums of +-1
#pragma unroll
    for (int k = 0; k < 8; ++k) {
        if (k < nk) {
            float2 kv = *(const float2*)(keys + ((size_t)(j0 + k) << 15) + d0);
            f0 += (d0 < fx[k])     ? (int)kv.x : -(int)kv.x;
            f1 += (d0 + 1 < fx[k]) ? (int)kv.y : -(int)kv.y;
        }
    }

    // pack: parity (bits 0-7), any3 count (bits 8-15), f+8 in [0,16] (bits 16-23)
    int m0 = (int)(sg0 >> 31) | (a30 << 8) | ((f0 + 8) << 16);
    int m1 = (int)(sg1 >> 31) | (a31 << 8) | ((f1 + 8) << 16);
    int2* dst = (int2*)(ws + (g << 15) + d0);
    *dst = make_int2(m0, m1);
}

// K2: combine 16 group-partials per dim. Sums stay carry-free per byte-field:
// parity<=16, any3<=64, sum(f_g+8)=F+128 in [8,248].
__global__ __launch_bounds__(256) void hdc_combine_kernel(
    const int* __restrict__ ws,
    float* __restrict__ out)
{
    int d = blockIdx.x * 256 + threadIdx.x;
    int m = 0;
#pragma unroll
    for (int g2 = 0; g2 < NG; ++g2)
        m += ws[(g2 << 15) + d];
    bool neg  = (m & 1) != 0;                 // parity of 64 sign bits
    bool any3 = ((m >> 8) & 0xFF) != 0;       // any |x+y+z| == 3
    int  F    = ((m >> 16) & 0xFF) - 128;     // feat_hv (exact integer)
    float o;
    if (F >= 0) o = neg ? -1.0f : 1.0f;
    else        o = (neg && any3) ? 1.0f : -1.0f;
    out[d] = o;
}

extern "C" void kernel_launch(void* const* d_in, const int* in_sizes, int n_in,
                              void* d_out, int out_size, void* d_ws, size_t ws_size,
                              hipStream_t stream) {
    const float* input = (const float*)d_in[0];
    const float* feat  = (const float*)d_in[1];
    const float* Wx    = (const float*)d_in[2];
    const float* Wy    = (const float*)d_in[3];
    const float* Wz    = (const float*)d_in[4];
    const float* Wt    = (const float*)d_in[5];
    const float* keys  = (const float*)d_in[6];
    float* out = (float*)d_out;
    int* ws = (int*)d_ws;                    // NG * 32768 ints = 2 MB

    dim3 grid1(NG * NC);                     // 256 blocks, 1/CU
    dim3 block1(TPB);
    hipLaunchKernelGGL(hdc_partial_kernel, grid1, block1, 0, stream,
                       input, feat, Wx, Wy, Wz, Wt, keys, ws);

    dim3 grid2(D_DIM / 256);                 // 128 blocks
    dim3 block2(256);
    hipLaunchKernelGGL(hdc_combine_kernel, grid2, block2, 0, stream,
                       ws, out);
}

// Round 7
// 14.160 us; speedup vs baseline: 1.2098x; 1.2098x over previous
//
#include <hip/hip_runtime.h>

#define D_DIM 32768
#define NT 64
#define NKEYS 120
#define TPB 1024
#define DB 128      // dims per block window
#define NW 16       // waves per block

__constant__ int c_feat_idx[NKEYS] = {
    557, 581, 553, 551, 92, 554, 579, 570, 573, 577,
    565, 286, 555, 549, 13, 550, 63, 580, 556, 564,
    0, 576, 567, 552, 578, 588, 597, 566, 571, 44,
    572, 574, 14, 582, 381, 594, 4, 593, 218, 25,
    84, 592, 3, 591, 547, 561, 562, 548, 319, 596,
    558, 563, 87, 65, 599, 17, 88, 2, 49, 309,
    6, 81, 15, 590, 589, 43, 273, 420, 546, 568,
    400, 277, 202, 287, 434, 435, 423, 431, 301, 417,
    412, 205, 179, 327, 176, 442, 172, 450, 391, 163,
    154, 480, 485, 490, 491, 498, 503, 507, 509, 452,
    239, 388, 219, 303, 292, 310, 316, 320, 322, 324,
    326, 330, 336, 263, 262, 339, 340, 256, 345, 347};

__device__ __forceinline__ int level_idx(float x) {
    // replicate: clip(x,-5,5); round(((x+5)/10)*2047) half-to-even; clip 0..2047
    x = fminf(fmaxf(x, -5.0f), 5.0f);
    float v = (x + 5.0f) / 10.0f * 2047.0f;
    int i = (int)rintf(v);
    return min(max(i, 0), 2047);
}

// R1 geometry (256 blocks x 16 waves, 128-dim window, single kernel, LDS
// combine) but half-wave-paired dwordx4 gathers: lanes 0-31 serve the even
// timestamp/key of each pair, lanes 32-63 the odd one; each lane covers 4
// dims. 12 VMEM instructions per wave instead of 24, same cache lines.
__global__ __launch_bounds__(TPB) void hdc_encode_kernel(
    const float* __restrict__ input,
    const float* __restrict__ feat,
    const float* __restrict__ Wx,
    const float* __restrict__ Wy,
    const float* __restrict__ Wz,
    const float* __restrict__ Wt,
    const float* __restrict__ keys,
    float* __restrict__ out)
{
    __shared__ int s_idx[4][NT];       // ix, iy, iz, it
    __shared__ int s_fidx[NKEYS];
    __shared__ int s_meta[NW][2][DB];  // packed per-dim partials, 16 KB

    const int tid = threadIdx.x;

    if (tid < NT) {
        s_idx[0][tid] = level_idx(input[tid * 4 + 1]);
        s_idx[1][tid] = level_idx(input[tid * 4 + 2]);
        s_idx[2][tid] = level_idx(input[tid * 4 + 3]);
        int it = (int)rintf((float)tid / 64.0f * 63.0f);
        s_idx[3][tid] = min(max(it, 0), NT - 1);
    } else if (tid < NT + NKEYS) {
        int j = tid - NT;
        float fv = feat[c_feat_idx[j]];
        fv = fminf(fmaxf(fv, -1.0f), 1.0f);
        s_fidx[j] = (int)rintf((fv + 1.0f) * 0.5f * 32768.0f);
    }
    __syncthreads();

    const int wave = tid >> 6;          // 0..15
    const int lane = tid & 63;
    const int half = lane >> 5;         // 0 = even element of pair, 1 = odd
    const int l32  = lane & 31;
    const int dloc = l32 * 4;           // 4 dims per lane
    const int d0   = blockIdx.x * DB + dloc;

    // packed per-dim accumulators: bits0-7 neg-sign count, bits8-15 any3
    // count, bits16-23 (f+4) added at the end
    int m0 = 0, m1 = 0, m2 = 0, m3 = 0;

    // ---- sample part: 4 timestamps as 2 half-wave pairs ----
    const int t0 = wave * 4;
#pragma unroll
    for (int p = 0; p < 2; ++p) {
        int myt = t0 + 2 * p + half;    // low half: even t, high half: odd t
        int rx = s_idx[0][myt];
        int ry = s_idx[1][myt];
        int rz = s_idx[2][myt];
        int rt = s_idx[3][myt];
        float4 x = *(const float4*)(Wx + ((size_t)rx << 15) + d0);
        float4 y = *(const float4*)(Wy + ((size_t)ry << 15) + d0);
        float4 z = *(const float4*)(Wz + ((size_t)rz << 15) + d0);
        float4 w = *(const float4*)(Wt + ((size_t)rt << 15) + d0);
        float s0 = x.x + y.x + z.x, s1 = x.y + y.y + z.y;
        float s2 = x.z + y.z + z.z, s3 = x.w + y.w + z.w;
        m0 += (int)(__float_as_uint(s0 * w.x) >> 31) + ((fabsf(s0) > 2.0f) ? 256 : 0);
        m1 += (int)(__float_as_uint(s1 * w.y) >> 31) + ((fabsf(s1) > 2.0f) ? 256 : 0);
        m2 += (int)(__float_as_uint(s2 * w.z) >> 31) + ((fabsf(s2) > 2.0f) ? 256 : 0);
        m3 += (int)(__float_as_uint(s3 * w.w) >> 31) + ((fabsf(s3) > 2.0f) ? 256 : 0);
    }

    // ---- feature part: up to 8 keys as 4 half-wave pairs ----
    const int nk = (wave < 8) ? 8 : 7;                 // 8*8 + 8*7 = 120
    const int j0 = (wave < 8) ? wave * 8 : 64 + (wave - 8) * 7;
    float f0 = 0.0f, f1 = 0.0f, f2 = 0.0f, f3 = 0.0f;  // exact small ints
#pragma unroll
    for (int q = 0; q < 4; ++q) {
        int jj = 2 * q + half;
        int j  = j0 + min(jj, nk - 1);                 // clamp keeps in-bounds
        int fx = s_fidx[j];
        float4 kv = *(const float4*)(keys + ((size_t)j << 15) + d0);
        if (jj < nk) {                                 // masked pad (nk==7, q==3, high half)
            f0 += (d0     < fx) ? kv.x : -kv.x;
            f1 += (d0 + 1 < fx) ? kv.y : -kv.y;
            f2 += (d0 + 2 < fx) ? kv.z : -kv.z;
            f3 += (d0 + 3 < fx) ? kv.w : -kv.w;
        }
    }
    m0 += ((int)f0 + 4) << 16;
    m1 += ((int)f1 + 4) << 16;
    m2 += ((int)f2 + 4) << 16;
    m3 += ((int)f3 + 4) << 16;

    *(int4*)&s_meta[wave][half][dloc] = make_int4(m0, m1, m2, m3);
    __syncthreads();

    // ---- combine: 32 partials per dim; byte fields stay carry-free:
    // neg<=64, any3<=64, sum(f+4)=F+128 in [8,248] ----
    if (tid < DB) {
        int m = 0;
#pragma unroll
        for (int e = 0; e < 2 * NW; ++e)
            m += s_meta[e >> 1][e & 1][tid];
        bool neg  = (m & 1) != 0;              // parity of 64 sign bits
        bool any3 = ((m >> 8) & 0xFF) != 0;    // any |x+y+z| == 3
        int  F    = ((m >> 16) & 0xFF) - 128;  // feat_hv exact integer
        float o;
        if (F >= 0) o = neg ? -1.0f : 1.0f;
        else        o = (neg && any3) ? 1.0f : -1.0f;
        out[blockIdx.x * DB + tid] = o;
    }
}

extern "C" void kernel_launch(void* const* d_in, const int* in_sizes, int n_in,
                              void* d_out, int out_size, void* d_ws, size_t ws_size,
                              hipStream_t stream) {
    const float* input = (const float*)d_in[0];
    const float* feat  = (const float*)d_in[1];
    const float* Wx    = (const float*)d_in[2];
    const float* Wy    = (const float*)d_in[3];
    const float* Wz    = (const float*)d_in[4];
    const float* Wt    = (const float*)d_in[5];
    const float* keys  = (const float*)d_in[6];
    float* out = (float*)d_out;

    dim3 grid(D_DIM / DB);   // 256 blocks -> one per CU
    dim3 block(TPB);
    hipLaunchKernelGGL(hdc_encode_kernel, grid, block, 0, stream,
                       input, feat, Wx, Wy, Wz, Wt, keys, out);
}

// Round 8
// 13.837 us; speedup vs baseline: 1.2380x; 1.0233x over previous
//
#include <hip/hip_runtime.h>

#define D_DIM 32768
#define NT 64
#define NKEYS 120
#define TPB 1024
#define DB 128      // dims per block
#define NW 16       // waves per block

__constant__ int c_feat_idx[NKEYS] = {
    557, 581, 553, 551, 92, 554, 579, 570, 573, 577,
    565, 286, 555, 549, 13, 550, 63, 580, 556, 564,
    0, 576, 567, 552, 578, 588, 597, 566, 571, 44,
    572, 574, 14, 582, 381, 594, 4, 593, 218, 25,
    84, 592, 3, 591, 547, 561, 562, 548, 319, 596,
    558, 563, 87, 65, 599, 17, 88, 2, 49, 309,
    6, 81, 15, 590, 589, 43, 273, 420, 546, 568,
    400, 277, 202, 287, 434, 435, 423, 431, 301, 417,
    412, 205, 179, 327, 176, 442, 172, 450, 391, 163,
    154, 480, 485, 490, 491, 498, 503, 507, 509, 452,
    239, 388, 219, 303, 292, 310, 316, 320, 322, 324,
    326, 330, 336, 263, 262, 339, 340, 256, 345, 347};

__device__ __forceinline__ int level_idx(float x) {
    // replicate: clip(x,-5,5); round(((x+5)/10)*2047) half-to-even; clip 0..2047
    x = fminf(fmaxf(x, -5.0f), 5.0f);
    float v = (x + 5.0f) / 10.0f * 2047.0f;
    int i = (int)rintf(v);
    return min(max(i, 0), 2047);
}

__global__ __launch_bounds__(TPB) void hdc_encode_kernel(
    const float* __restrict__ input,
    const float* __restrict__ feat,
    const float* __restrict__ Wx,
    const float* __restrict__ Wy,
    const float* __restrict__ Wz,
    const float* __restrict__ Wt,
    const float* __restrict__ keys,
    float* __restrict__ out)
{
    __shared__ int   s_idx[4][NT];     // ix, iy, iz, it
    __shared__ int   s_fidx[NKEYS];
    __shared__ int   s_meta[NW][DB];   // bit0..7: sign count, bit8+: any3 count
    __shared__ float s_f[NW][DB];

    const int tid = threadIdx.x;

    if (tid < NT) {
        float x = input[tid * 4 + 1];
        float y = input[tid * 4 + 2];
        float z = input[tid * 4 + 3];
        s_idx[0][tid] = level_idx(x);
        s_idx[1][tid] = level_idx(y);
        s_idx[2][tid] = level_idx(z);
        float tv = (float)tid;
        int it = (int)rintf(tv / 64.0f * 63.0f);
        s_idx[3][tid] = min(max(it, 0), NT - 1);
    } else if (tid < NT + NKEYS) {
        int j = tid - NT;
        float fv = feat[c_feat_idx[j]];
        fv = fminf(fmaxf(fv, -1.0f), 1.0f);
        s_fidx[j] = (int)rintf((fv + 1.0f) * 0.5f * 32768.0f);
    }
    __syncthreads();

    const int wave = __builtin_amdgcn_readfirstlane(tid >> 6);  // 0..15, wave-uniform SGPR
    const int lane = tid & 63;
    const int d0 = (blockIdx.x << 7) + lane * 2;   // this lane's two dims: d0, d0+1

    // --- sample part: 4 timestamps per wave-slice ---
    unsigned sg0 = 0u, sg1 = 0u;
    int a30 = 0, a31 = 0;
    const int t0 = wave * 4;
#pragma unroll
    for (int k = 0; k < 4; ++k) {
        int t = t0 + k;
        int ix = __builtin_amdgcn_readfirstlane(s_idx[0][t]);
        int iy = __builtin_amdgcn_readfirstlane(s_idx[1][t]);
        int iz = __builtin_amdgcn_readfirstlane(s_idx[2][t]);
        int it = __builtin_amdgcn_readfirstlane(s_idx[3][t]);
        float2 x = *(const float2*)(Wx + ((size_t)ix << 15) + d0);
        float2 y = *(const float2*)(Wy + ((size_t)iy << 15) + d0);
        float2 z = *(const float2*)(Wz + ((size_t)iz << 15) + d0);
        float2 w = *(const float2*)(Wt + ((size_t)it << 15) + d0);
        float sA = x.x + y.x + z.x;          // in {±1, ±3} exactly
        float sB = x.y + y.y + z.y;
        sg0 ^= __float_as_uint(sA * w.x);
        sg1 ^= __float_as_uint(sB * w.y);
        a30 |= (fabsf(sA) > 2.0f) ? 1 : 0;
        a31 |= (fabsf(sB) > 2.0f) ? 1 : 0;
    }

    // --- feature part: 8 keys for waves 0..7, 7 keys for waves 8..15 ---
    float f0 = 0.0f, f1 = 0.0f;
    if (wave < 8) {
        const int j0 = wave * 8;
#pragma unroll
        for (int k = 0; k < 8; ++k) {
            int j = j0 + k;
            int fx = __builtin_amdgcn_readfirstlane(s_fidx[j]);
            float2 kv = *(const float2*)(keys + ((size_t)j << 15) + d0);
            f0 += (d0 < fx) ? kv.x : -kv.x;
            f1 += (d0 + 1 < fx) ? kv.y : -kv.y;
        }
    } else {
        const int j0 = 64 + (wave - 8) * 7;
#pragma unroll
        for (int k = 0; k < 7; ++k) {
            int j = j0 + k;
            int fx = __builtin_amdgcn_readfirstlane(s_fidx[j]);
            float2 kv = *(const float2*)(keys + ((size_t)j << 15) + d0);
            f0 += (d0 < fx) ? kv.x : -kv.x;
            f1 += (d0 + 1 < fx) ? kv.y : -kv.y;
        }
    }

    const int col = lane * 2;
    s_meta[wave][col]     = (int)(sg0 >> 31) | (a30 << 8);
    s_meta[wave][col + 1] = (int)(sg1 >> 31) | (a31 << 8);
    s_f[wave][col]     = f0;
    s_f[wave][col + 1] = f1;
    __syncthreads();

    if (tid < DB) {
        int msum = 0;
        float f = 0.0f;
#pragma unroll
        for (int w2 = 0; w2 < NW; ++w2) {
            msum += s_meta[w2][tid];
            f    += s_f[w2][tid];
        }
        bool neg  = (msum & 1) != 0;          // parity of sign bits = sign of product
        bool any3 = (msum & 0xFF00) != 0;     // any |x+y+z| == 3
        float o;
        if (f >= 0.0f) o = neg ? -1.0f : 1.0f;
        else           o = (neg && any3) ? 1.0f : -1.0f;
        out[(blockIdx.x << 7) + tid] = o;
    }
}

extern "C" void kernel_launch(void* const* d_in, const int* in_sizes, int n_in,
                              void* d_out, int out_size, void* d_ws, size_t ws_size,
                              hipStream_t stream) {
    const float* input = (const float*)d_in[0];
    const float* feat  = (const float*)d_in[1];
    const float* Wx    = (const float*)d_in[2];
    const float* Wy    = (const float*)d_in[3];
    const float* Wz    = (const float*)d_in[4];
    const float* Wt    = (const float*)d_in[5];
    const float* keys  = (const float*)d_in[6];
    float* out = (float*)d_out;

    dim3 grid(D_DIM / DB);   // 256 blocks -> one per CU
    dim3 block(TPB);
    hipLaunchKernelGGL(hdc_encode_kernel, grid, block, 0, stream,
                       input, feat, Wx, Wy, Wz, Wt, keys, out);
}